// Round 14
// baseline (143.653 us; speedup 1.0000x reference)
//
#include <hip/hip_runtime.h>
#include <hip/hip_bf16.h>

#define BS 32768
#define NWP 10
#define DD 256
#define NEXP 6
#define HH 64
#define OUT_DIM 2
#define IB 8                 // consecutive items per block
#define RPB (IB * NWP)       // 80 rows per block

typedef short bf16x8 __attribute__((ext_vector_type(8)));
typedef float f32x4 __attribute__((ext_vector_type(4)));

__device__ inline short bfs(float f) {
  __hip_bfloat16 h = __float2bfloat16(f);   // RNE
  return __builtin_bit_cast(short, h);
}

// ------- kernel 1: prep W1T bf16 [e][h][d] (blocks 0-11) + rw (blocks 12-17) -------
__global__ __launch_bounds__(1024) void aux_k(const float* __restrict__ W1,
                                              const float* __restrict__ re,
                                              const float* __restrict__ b1,
                                              short* __restrict__ W1T,
                                              float* __restrict__ rw) {
  const int bid = blockIdx.x;
  const int tid = threadIdx.x;
  if (bid < 12) {               // W1 -> W1T bf16 [e][h][d]
    const int e = bid >> 1;
    const int h = (bid & 1) * 32 + (tid >> 5);
    const int d0 = (tid & 31) * 8;
    const float* wp = W1 + (size_t)e * DD * HH + h;
    bf16x8 v;
    #pragma unroll
    for (int i = 0; i < 8; ++i) v[i] = bfs(wp[(size_t)(d0 + i) * HH]);
    *(bf16x8*)(W1T + ((size_t)e * HH + h) * DD + d0) = v;
  } else {                      // rw[e][n][h] = b1 + re·W1 (fp32 exact)
    const int e = bid - 12;
    if (tid < NWP * HH) {
      const int n = tid >> 6, h = tid & 63;
      const float* rp = re + (size_t)n * DD;
      const float* wp = W1 + (size_t)e * DD * HH + h;
      float s = b1[e * HH + h];
      for (int d = 0; d < DD; ++d) s += rp[d] * wp[(size_t)d * HH];
      rw[((size_t)e * NWP + n) * HH + h] = s;
    }
  }
}

// ------- kernel 2: sequential-stream GEMM; local expert sort; quadrant waves -------
__global__ __launch_bounds__(256, 3) void moe_gemm_k(
    const float* __restrict__ x,
    const int* __restrict__ cmd,
    const short* __restrict__ W1T,     // [6][64][256] bf16, L2-resident
    const float* __restrict__ rwg,     // [6][10][64] f32 (b1 + re·W1), L2-hot
    const float* __restrict__ W2,
    const float* __restrict__ b2,
    float* __restrict__ out)
{
  __shared__ short Xb[RPB * DD];       // 40 KB: 80 sorted bf16 rows, XOR-swizzled
  __shared__ float po[RPB][4][2];      // 2.5 KB: per-quadrant partials (no atomics)
  __shared__ int pm[IB];               // sorted order -> local item idx
  __shared__ int se[IB];               // sorted item experts
  __shared__ int rb[IB + 1];           // run boundaries in sorted-row space
  __shared__ int eg[IB];               // run experts
  __shared__ int nrun_s;
  __shared__ int eload[IB];

  const int b0 = blockIdx.x * IB;      // 8 consecutive items: 80 KB contiguous x
  const int tid = threadIdx.x;
  const int lane = tid & 63;
  const int wv = tid >> 6;
  const int arow = lane & 15;
  const int ag = lane >> 4;

  if (tid < IB) eload[tid] = cmd[b0 + tid];
  __syncthreads();

  if (tid == 0) {                      // stable insertion sort of 8 items by expert
    int ei[IB], id[IB];
    #pragma unroll
    for (int i = 0; i < IB; ++i) { ei[i] = eload[i]; id[i] = i; }
    #pragma unroll
    for (int i = 1; i < IB; ++i) {
      const int ev = ei[i], iv = id[i];
      int j = i - 1;
      while (j >= 0 && ei[j] > ev) { ei[j+1] = ei[j]; id[j+1] = id[j]; --j; }
      ei[j+1] = ev; id[j+1] = iv;
    }
    int nr = 0;
    #pragma unroll
    for (int i = 0; i < IB; ++i) {
      pm[i] = id[i]; se[i] = ei[i];
      if (i == 0 || ei[i] != ei[i-1]) { rb[nr] = i * NWP; eg[nr] = ei[i]; ++nr; }
    }
    rb[nr] = RPB;
    nrun_s = nr;
  }
  __syncthreads();

  // ---- stage 80 rows in SORTED order; global reads stay inside the block's
  //      contiguous 80 KB window (sequential at DRAM granularity)
  {
    const int g0 = b0 + pm[wv * 2];
    const int g1 = b0 + pm[wv * 2 + 1];
    #pragma unroll
    for (int i = 0; i < 20; ++i) {
      const int gitem = (i < 10) ? g0 : g1;
      const int n = (i < 10) ? i : i - 10;
      const int s = wv * 20 + i;
      const f32x4 xv = __builtin_nontemporal_load(
          (const f32x4*)(x + ((size_t)gitem * NWP + n) * DD + lane * 4));
      short4 pk = make_short4(bfs(xv[0]), bfs(xv[1]), bfs(xv[2]), bfs(xv[3]));
      *(short4*)&Xb[s * DD + ((lane * 4) ^ ((s & 7) << 3))] = pk;
    }
  }
  __syncthreads();

  // ---- per expert-run MFMA passes; wave wv owns h-quadrant [wv*16, wv*16+16)
  const int nrun = nrun_s;
  for (int g = 0; g < nrun; ++g) {
    const int r0 = rb[g], r1 = rb[g + 1];
    const int e = eg[g];
    // Wq: this wave's quadrant fragments for expert e (8 KB from L2 per pass)
    const short* wq = W1T + ((size_t)e * HH + wv * 16 + arow) * DD + ag * 8;
    bf16x8 Wq[8];
    #pragma unroll
    for (int ks = 0; ks < 8; ++ks) Wq[ks] = *(const bf16x8*)(wq + ks * 32);
    const int h0 = wv * 16 + ag * 4;
    const float4 wa = *(const float4*)(W2 + ((size_t)e * HH + h0) * OUT_DIM);
    const float4 wb = *(const float4*)(W2 + ((size_t)e * HH + h0 + 2) * OUT_DIM);

    const int t0 = r0 >> 4, t1 = (r1 - 1) >> 4;
    for (int t = t0; t <= t1; ++t) {
      const int row = t * 16 + arow;           // sorted-row this lane covers
      f32x4 acc = {0.f, 0.f, 0.f, 0.f};
      #pragma unroll
      for (int ks = 0; ks < 8; ++ks) {
        const int kidx = ks * 32 + ag * 8;
        const bf16x8 bx = *(const bf16x8*)&Xb[row * DD + (kidx ^ ((arow & 7) << 3))];
        acc = __builtin_amdgcn_mfma_f32_16x16x32_bf16(Wq[ks], bx, acc, 0, 0, 0);
      }
      // epilogue: relu(acc + rw[e][n][h]) @ W2, reduce over ag (quadrant h's)
      const int n = row - (row / NWP) * NWP;
      const float4 rv = *(const float4*)(rwg + ((size_t)e * NWP + n) * HH + h0);
      const float h0v = fmaxf(acc[0] + rv.x, 0.f);
      const float h1v = fmaxf(acc[1] + rv.y, 0.f);
      const float h2v = fmaxf(acc[2] + rv.z, 0.f);
      const float h3v = fmaxf(acc[3] + rv.w, 0.f);
      float p0 = h0v * wa.x + h1v * wa.z + h2v * wb.x + h3v * wb.z;
      float p1 = h0v * wa.y + h1v * wa.w + h2v * wb.y + h3v * wb.w;
      p0 += __shfl_xor(p0, 16); p1 += __shfl_xor(p1, 16);
      p0 += __shfl_xor(p0, 32); p1 += __shfl_xor(p1, 32);
      if (ag == 0 && row >= r0 && row < r1) {  // rows of THIS run only
        po[row][wv][0] = p0;                   // unique writer per (row, wv)
        po[row][wv][1] = p1;
      }
    }
  }

  __syncthreads();

  // ---- fused cumsum + writeout: one thread per item (sorted position j)
  if (tid < IB) {
    const int j = tid;
    const int gitem = b0 + pm[j];
    const int e = se[j];
    const float bb0 = b2[e * OUT_DIM + 0];
    const float bb1 = b2[e * OUT_DIM + 1];
    float v[NWP * OUT_DIM];
    float s0 = 0.f, s1 = 0.f;
    #pragma unroll
    for (int n = 0; n < NWP; ++n) {
      const int row = j * NWP + n;
      s0 += po[row][0][0] + po[row][1][0] + po[row][2][0] + po[row][3][0] + bb0;
      s1 += po[row][0][1] + po[row][1][1] + po[row][2][1] + po[row][3][1] + bb1;
      v[n * 2 + 0] = s0;
      v[n * 2 + 1] = s1;
    }
    float4* op = (float4*)(out + (size_t)gitem * NWP * OUT_DIM);
    #pragma unroll
    for (int q = 0; q < 5; ++q)
      op[q] = make_float4(v[q * 4], v[q * 4 + 1], v[q * 4 + 2], v[q * 4 + 3]);
  }
}

extern "C" void kernel_launch(void* const* d_in, const int* in_sizes, int n_in,
                              void* d_out, int out_size, void* d_ws, size_t ws_size,
                              hipStream_t stream) {
  const float* x          = (const float*)d_in[0];
  const int*   meas       = (const int*)d_in[1];
  const float* rank_embed = (const float*)d_in[2];
  const float* W1         = (const float*)d_in[3];
  const float* b1         = (const float*)d_in[4];
  const float* W2         = (const float*)d_in[5];
  const float* b2         = (const float*)d_in[6];
  float* out = (float*)d_out;

  short* W1T = (short*)d_ws;                                // 192 KB bf16
  float* rw  = (float*)((char*)d_ws + (256 << 10));         // 15.4 KB f32

  aux_k<<<18, 1024, 0, stream>>>(W1, rank_embed, b1, W1T, rw);
  moe_gemm_k<<<BS / IB, 256, 0, stream>>>(x, meas, W1T, rw, W2, b2, out);
}

// Round 15
// 106.639 us; speedup vs baseline: 1.3471x; 1.3471x over previous
//
#include <hip/hip_runtime.h>
#include <hip/hip_bf16.h>

#define BS 32768
#define NWP 10
#define DD 256
#define NEXP 6
#define HH 64
#define OUT_DIM 2
#define MB 64
#define MAXQ 524    // >= sum_e ceil(cnt_e/MB) worst case (518)

typedef short bf16x8 __attribute__((ext_vector_type(8)));
typedef float f32x4 __attribute__((ext_vector_type(4)));

__device__ inline short bfs(float f) {
  __hip_bfloat16 h = __float2bfloat16(f);   // RNE
  return __builtin_bit_cast(short, h);
}

// ------- kernel 1 (fused aux): blocks 0-31 bucket; 32-43 W1T; 44-49 rw -------
__global__ __launch_bounds__(1024) void aux_k(const int* __restrict__ cmd,
                                              const float* __restrict__ W1,
                                              const float* __restrict__ re,
                                              const float* __restrict__ b1,
                                              int* __restrict__ counts,
                                              int* __restrict__ lists,
                                              short* __restrict__ W1T,
                                              float* __restrict__ rw) {
  const int bid = blockIdx.x;
  const int tid = threadIdx.x;

  if (bid < 32) {               // ---- bucket by expert (block-aggregated atomics)
    __shared__ int wcnt[16][NEXP];
    __shared__ int wbase[16][NEXP];
    const int w = tid >> 6, lane = tid & 63;
    const int b = bid * 1024 + tid;               // grid covers exactly BS
    const int e = cmd[b];
    #pragma unroll
    for (int ee = 0; ee < NEXP; ++ee) {
      unsigned long long m = __ballot(e == ee);
      if (lane == 0) wcnt[w][ee] = __popcll(m);
    }
    __syncthreads();
    if (tid < NEXP) {
      int tot = 0, pf[16];
      #pragma unroll
      for (int ww = 0; ww < 16; ++ww) { pf[ww] = tot; tot += wcnt[ww][tid]; }
      const int bb = atomicAdd(&counts[tid], tot);
      #pragma unroll
      for (int ww = 0; ww < 16; ++ww) wbase[ww][tid] = bb + pf[ww];
    }
    __syncthreads();
    #pragma unroll
    for (int ee = 0; ee < NEXP; ++ee) {
      unsigned long long m = __ballot(e == ee);   // same mask as pass 1
      if (e == ee) {
        const int nbelow = __popcll(m & ((1ull << lane) - 1ull));
        lists[ee * BS + wbase[w][ee] + nbelow] = b;
      }
    }
  } else if (bid < 44) {        // ---- W1 -> W1T bf16 [e][h][d]
    const int e = (bid - 32) >> 1;
    const int h = ((bid - 32) & 1) * 32 + (tid >> 5);
    const int d0 = (tid & 31) * 8;
    const float* wp = W1 + (size_t)e * DD * HH + h;
    bf16x8 v;
    #pragma unroll
    for (int i = 0; i < 8; ++i) v[i] = bfs(wp[(size_t)(d0 + i) * HH]);
    *(bf16x8*)(W1T + ((size_t)e * HH + h) * DD + d0) = v;
  } else {                      // ---- rw[e][n][h] = b1 + re·W1 (fp32 exact)
    const int e = bid - 44;
    if (tid < NWP * HH) {
      const int n = tid >> 6, h = tid & 63;
      const float* rp = re + (size_t)n * DD;
      const float* wp = W1 + (size_t)e * DD * HH + h;
      float s = b1[e * HH + h];
      for (int d = 0; d < DD; ++d) s += rp[d] * wp[(size_t)d * HH];
      rw[((size_t)e * NWP + n) * HH + h] = s;
    }
  }
}

// ------- kernel 2: R13 body verbatim; MB=64 (halved prologue count) -------
__global__ __launch_bounds__(256, 2) void moe_gemm_k(
    const float* __restrict__ x,
    const short* __restrict__ W1T,     // [6][64][256] bf16, L2-resident
    const float* __restrict__ rwg,     // [6][10][64] f32 (b1 + re·W1)
    const float* __restrict__ W2,
    const float* __restrict__ b2,
    const int* __restrict__ qmeta,     // [0..5] counts
    const int* __restrict__ lists,
    float* __restrict__ out)
{
  __shared__ short Xa[4][16 * DD];     // 32 KB per-wave single-buffer tiles
  __shared__ float rwl[NWP][68];       // 2.72 KB rw[e]
  __shared__ float w2l[HH * OUT_DIM];  // 0.5 KB  W2[e]
  __shared__ float po[MB * NWP][2];    // 5.12 KB pre-cumsum outputs

  // decode (e, start) from blockIdx
  const int wi = blockIdx.x;
  int acc0 = 0, e = -1, start = 0;
  #pragma unroll
  for (int ee = 0; ee < NEXP; ++ee) {
    const int nc = (qmeta[ee] + MB - 1) >> 6;
    if (e < 0 && wi < acc0 + nc) { e = ee; start = (wi - acc0) * MB; }
    acc0 += nc;
  }
  if (e < 0) return;
  const int cnt = qmeta[e];
  const int nb = min(MB, cnt - start);
  const int nrows = nb * NWP;

  const int tid = threadIdx.x;
  const int lane = tid & 63;
  const int wv = tid >> 6;
  const int arow = lane & 15;
  const int ag = lane >> 4;
  const int lbase = e * BS + start;

  // hoist all A-fragments: Wf[nt][ks] = W1T[h=nt*16+arow][ks*32+ag*8 .. +8)
  bf16x8 Wf[4][8];                     // 128 VGPR, static indices only
  {
    const short* wb = W1T + ((size_t)e * HH + arow) * DD + ag * 8;
    #pragma unroll
    for (int nt = 0; nt < 4; ++nt)
      #pragma unroll
      for (int ks = 0; ks < 8; ++ks)
        Wf[nt][ks] = *(const bf16x8*)(wb + (size_t)(nt * 16) * DD + ks * 32);
  }
  for (int i = tid; i < NWP * HH; i += 256)
    rwl[i >> 6][i & 63] = rwg[(size_t)e * NWP * HH + i];
  if (tid < HH * OUT_DIM) w2l[tid] = W2[(size_t)e * HH * OUT_DIM + tid];

  __syncthreads();   // tables ready; no barriers until cumsum

  short* Xw = &Xa[wv][0];
  const int ntile = (nrows + 15) >> 4;

  for (int t = wv; t < ntile; t += 4) {          // tiles disjoint per wave
    // stage 16 rows: coalesced 1KB/instr non-temporal loads (x has zero reuse)
    #pragma unroll
    for (int r = 0; r < 16; ++r) {
      const int rowu = __builtin_amdgcn_readfirstlane(min(t * 16 + r, nrows - 1));
      const int item = rowu / NWP;
      const int nn = rowu - item * NWP;
      const int gb = lists[lbase + item];        // uniform address -> scalar load
      const f32x4 xv = __builtin_nontemporal_load(
          (const f32x4*)(x + ((size_t)gb * NWP + nn) * DD + lane * 4));
      short4 pk = make_short4(bfs(xv[0]), bfs(xv[1]), bfs(xv[2]), bfs(xv[3]));
      *(short4*)&Xw[r * DD + ((lane * 4) ^ ((r & 7) << 3))] = pk;
    }

    // compute: S^T = W1^T · x ; only 8 ds_reads per tile
    f32x4 acc[4] = {{0,0,0,0},{0,0,0,0},{0,0,0,0},{0,0,0,0}};
    #pragma unroll
    for (int ks = 0; ks < 8; ++ks) {
      const int kidx = ks * 32 + ag * 8;
      const bf16x8 bx = *(const bf16x8*)&Xw[arow * DD + (kidx ^ ((arow & 7) << 3))];
      #pragma unroll
      for (int nt = 0; nt < 4; ++nt)
        acc[nt] = __builtin_amdgcn_mfma_f32_16x16x32_bf16(Wf[nt][ks], bx, acc[nt], 0, 0, 0);
    }

    // thin epilogue: lane owns batch-row t*16+arow; h = nt*16+ag*4+rg
    const int row = t * 16 + arow;
    const int rowc = min(row, nrows - 1);
    const int nn = rowc - (rowc / NWP) * NWP;
    float p0 = 0.f, p1 = 0.f;
    #pragma unroll
    for (int nt = 0; nt < 4; ++nt) {
      const int h0 = nt * 16 + ag * 4;
      const float4 rv = *(const float4*)&rwl[nn][h0];
      const float4 wa = *(const float4*)&w2l[h0 * 2];       // h0:{o0,o1} h1:{o0,o1}
      const float4 wb = *(const float4*)&w2l[h0 * 2 + 4];   // h2,h3
      const float h0v = fmaxf(acc[nt][0] + rv.x, 0.f);
      const float h1v = fmaxf(acc[nt][1] + rv.y, 0.f);
      const float h2v = fmaxf(acc[nt][2] + rv.z, 0.f);
      const float h3v = fmaxf(acc[nt][3] + rv.w, 0.f);
      p0 += h0v * wa.x + h1v * wa.z + h2v * wb.x + h3v * wb.z;
      p1 += h0v * wa.y + h1v * wa.w + h2v * wb.y + h3v * wb.w;
    }
    p0 += __shfl_xor(p0, 16); p1 += __shfl_xor(p1, 16);     // reduce over ag
    p0 += __shfl_xor(p0, 32); p1 += __shfl_xor(p1, 32);
    if (ag == 0 && row < nrows) {     // unique writer: tiles disjoint per wave
      po[row][0] = p0;
      po[row][1] = p1;
    }
  }

  __syncthreads();   // all po stores visible

  // fused cumsum + writeout: one thread per batch item
  if (tid < nb) {
    const int gb = lists[lbase + tid];
    const float bb0 = b2[e * OUT_DIM + 0];
    const float bb1 = b2[e * OUT_DIM + 1];
    float v[NWP * OUT_DIM];
    float s0 = 0.f, s1 = 0.f;
    #pragma unroll
    for (int n = 0; n < NWP; ++n) {
      s0 += po[tid * NWP + n][0] + bb0;
      s1 += po[tid * NWP + n][1] + bb1;
      v[n * 2 + 0] = s0;
      v[n * 2 + 1] = s1;
    }
    float4* op = (float4*)(out + (size_t)gb * NWP * OUT_DIM);
    #pragma unroll
    for (int q = 0; q < 5; ++q)
      op[q] = make_float4(v[q * 4], v[q * 4 + 1], v[q * 4 + 2], v[q * 4 + 3]);
  }
}

extern "C" void kernel_launch(void* const* d_in, const int* in_sizes, int n_in,
                              void* d_out, int out_size, void* d_ws, size_t ws_size,
                              hipStream_t stream) {
  const float* x          = (const float*)d_in[0];
  const int*   meas       = (const int*)d_in[1];
  const float* rank_embed = (const float*)d_in[2];
  const float* W1         = (const float*)d_in[3];
  const float* b1         = (const float*)d_in[4];
  const float* W2         = (const float*)d_in[5];
  const float* b2         = (const float*)d_in[6];
  float* out = (float*)d_out;

  int* qmeta = (int*)d_ws;                                       // counts[6]
  int* lists = (int*)((char*)d_ws + 8192);                       // 768 KB
  short* W1T = (short*)((char*)d_ws + (800 << 10));              // 192 KB bf16
  float* rw  = (float*)((char*)d_ws + (1000 << 10));             // 15.4 KB f32

  hipMemsetAsync(d_ws, 0, 256, stream);   // zero counts
  aux_k<<<50, 1024, 0, stream>>>(meas, W1, rank_embed, b1, qmeta, lists, W1T, rw);
  moe_gemm_k<<<MAXQ, 256, 0, stream>>>(x, W1T, rw, W2, b2, qmeta, lists, out);
}

// Round 16
// 100.913 us; speedup vs baseline: 1.4235x; 1.0567x over previous
//
#include <hip/hip_runtime.h>
#include <hip/hip_bf16.h>

#define BS 32768
#define NWP 10
#define DD 256
#define NEXP 6
#define HH 64
#define OUT_DIM 2
#define MB 32
#define MAXQ 1032   // >= sum_e ceil(cnt_e/MB) worst case

typedef short bf16x8 __attribute__((ext_vector_type(8)));
typedef float f32x4 __attribute__((ext_vector_type(4)));

__device__ inline short bfs(float f) {
  __hip_bfloat16 h = __float2bfloat16(f);   // RNE
  return __builtin_bit_cast(short, h);
}

// ------- kernel 1 (fused aux): blocks 0-31 bucket; 32-43 W1T; 44-49 rw -------
__global__ __launch_bounds__(1024) void aux_k(const int* __restrict__ cmd,
                                              const float* __restrict__ W1,
                                              const float* __restrict__ re,
                                              const float* __restrict__ b1,
                                              int* __restrict__ counts,
                                              int* __restrict__ lists,
                                              short* __restrict__ W1T,
                                              float* __restrict__ rw) {
  const int bid = blockIdx.x;
  const int tid = threadIdx.x;

  if (bid < 32) {               // ---- bucket by expert (block-aggregated atomics)
    __shared__ int wcnt[16][NEXP];
    __shared__ int wbase[16][NEXP];
    const int w = tid >> 6, lane = tid & 63;
    const int b = bid * 1024 + tid;               // grid covers exactly BS
    const int e = cmd[b];
    #pragma unroll
    for (int ee = 0; ee < NEXP; ++ee) {
      unsigned long long m = __ballot(e == ee);
      if (lane == 0) wcnt[w][ee] = __popcll(m);
    }
    __syncthreads();
    if (tid < NEXP) {
      int tot = 0, pf[16];
      #pragma unroll
      for (int ww = 0; ww < 16; ++ww) { pf[ww] = tot; tot += wcnt[ww][tid]; }
      const int bb = atomicAdd(&counts[tid], tot);
      #pragma unroll
      for (int ww = 0; ww < 16; ++ww) wbase[ww][tid] = bb + pf[ww];
    }
    __syncthreads();
    #pragma unroll
    for (int ee = 0; ee < NEXP; ++ee) {
      unsigned long long m = __ballot(e == ee);   // same mask as pass 1
      if (e == ee) {
        const int nbelow = __popcll(m & ((1ull << lane) - 1ull));
        lists[ee * BS + wbase[w][ee] + nbelow] = b;
      }
    }
  } else if (bid < 44) {        // ---- W1 -> W1T bf16 [e][h][d]
    const int e = (bid - 32) >> 1;
    const int h = ((bid - 32) & 1) * 32 + (tid >> 5);
    const int d0 = (tid & 31) * 8;
    const float* wp = W1 + (size_t)e * DD * HH + h;
    bf16x8 v;
    #pragma unroll
    for (int i = 0; i < 8; ++i) v[i] = bfs(wp[(size_t)(d0 + i) * HH]);
    *(bf16x8*)(W1T + ((size_t)e * HH + h) * DD + d0) = v;
  } else {                      // ---- rw[e][n][h] = b1 + re·W1 (fp32 exact)
    const int e = bid - 44;
    if (tid < NWP * HH) {
      const int n = tid >> 6, h = tid & 63;
      const float* rp = re + (size_t)n * DD;
      const float* wp = W1 + (size_t)e * DD * HH + h;
      float s = b1[e * HH + h];
      for (int d = 0; d < DD; ++d) s += rp[d] * wp[(size_t)d * HH];
      rw[((size_t)e * NWP + n) * HH + h] = s;
    }
  }
}

// ------- kernel 2: R13 body verbatim (MB=32, measured optimum) -------
__global__ __launch_bounds__(256, 2) void moe_gemm_k(
    const float* __restrict__ x,
    const short* __restrict__ W1T,     // [6][64][256] bf16, L2-resident
    const float* __restrict__ rwg,     // [6][10][64] f32 (b1 + re·W1)
    const float* __restrict__ W2,
    const float* __restrict__ b2,
    const int* __restrict__ qmeta,     // [0..5] counts
    const int* __restrict__ lists,
    float* __restrict__ out)
{
  __shared__ short Xa[4][16 * DD];     // 32 KB per-wave single-buffer tiles
  __shared__ float rwl[NWP][68];       // 2.72 KB rw[e]
  __shared__ float w2l[HH * OUT_DIM];  // 0.5 KB  W2[e]
  __shared__ float po[MB * NWP][2];    // 2.56 KB pre-cumsum outputs

  // decode (e, start) from blockIdx (no build_q kernel)
  const int wi = blockIdx.x;
  int acc0 = 0, e = -1, start = 0;
  #pragma unroll
  for (int ee = 0; ee < NEXP; ++ee) {
    const int nc = (qmeta[ee] + MB - 1) >> 5;
    if (e < 0 && wi < acc0 + nc) { e = ee; start = (wi - acc0) * MB; }
    acc0 += nc;
  }
  if (e < 0) return;
  const int cnt = qmeta[e];
  const int nb = min(MB, cnt - start);
  const int nrows = nb * NWP;

  const int tid = threadIdx.x;
  const int lane = tid & 63;
  const int wv = tid >> 6;
  const int arow = lane & 15;
  const int ag = lane >> 4;
  const int lbase = e * BS + start;

  // hoist all A-fragments: Wf[nt][ks] = W1T[h=nt*16+arow][ks*32+ag*8 .. +8)
  bf16x8 Wf[4][8];                     // 128 VGPR, static indices only
  {
    const short* wb = W1T + ((size_t)e * HH + arow) * DD + ag * 8;
    #pragma unroll
    for (int nt = 0; nt < 4; ++nt)
      #pragma unroll
      for (int ks = 0; ks < 8; ++ks)
        Wf[nt][ks] = *(const bf16x8*)(wb + (size_t)(nt * 16) * DD + ks * 32);
  }
  for (int i = tid; i < NWP * HH; i += 256)
    rwl[i >> 6][i & 63] = rwg[(size_t)e * NWP * HH + i];
  if (tid < HH * OUT_DIM) w2l[tid] = W2[(size_t)e * HH * OUT_DIM + tid];

  __syncthreads();   // tables ready; no barriers until cumsum

  short* Xw = &Xa[wv][0];
  const int ntile = (nrows + 15) >> 4;

  for (int t = wv; t < ntile; t += 4) {          // tiles disjoint per wave
    // stage 16 rows: coalesced 1KB/instr non-temporal loads (x has zero reuse)
    #pragma unroll
    for (int r = 0; r < 16; ++r) {
      const int rowu = __builtin_amdgcn_readfirstlane(min(t * 16 + r, nrows - 1));
      const int item = rowu / NWP;
      const int nn = rowu - item * NWP;
      const int gb = lists[lbase + item];        // uniform address -> scalar load
      const f32x4 xv = __builtin_nontemporal_load(
          (const f32x4*)(x + ((size_t)gb * NWP + nn) * DD + lane * 4));
      short4 pk = make_short4(bfs(xv[0]), bfs(xv[1]), bfs(xv[2]), bfs(xv[3]));
      *(short4*)&Xw[r * DD + ((lane * 4) ^ ((r & 7) << 3))] = pk;
    }

    // compute: S^T = W1^T · x ; only 8 ds_reads per tile
    f32x4 acc[4] = {{0,0,0,0},{0,0,0,0},{0,0,0,0},{0,0,0,0}};
    #pragma unroll
    for (int ks = 0; ks < 8; ++ks) {
      const int kidx = ks * 32 + ag * 8;
      const bf16x8 bx = *(const bf16x8*)&Xw[arow * DD + (kidx ^ ((arow & 7) << 3))];
      #pragma unroll
      for (int nt = 0; nt < 4; ++nt)
        acc[nt] = __builtin_amdgcn_mfma_f32_16x16x32_bf16(Wf[nt][ks], bx, acc[nt], 0, 0, 0);
    }

    // thin epilogue: lane owns batch-row t*16+arow; h = nt*16+ag*4+rg
    const int row = t * 16 + arow;
    const int rowc = min(row, nrows - 1);
    const int nn = rowc - (rowc / NWP) * NWP;
    float p0 = 0.f, p1 = 0.f;
    #pragma unroll
    for (int nt = 0; nt < 4; ++nt) {
      const int h0 = nt * 16 + ag * 4;
      const float4 rv = *(const float4*)&rwl[nn][h0];
      const float4 wa = *(const float4*)&w2l[h0 * 2];       // h0:{o0,o1} h1:{o0,o1}
      const float4 wb = *(const float4*)&w2l[h0 * 2 + 4];   // h2,h3
      const float h0v = fmaxf(acc[nt][0] + rv.x, 0.f);
      const float h1v = fmaxf(acc[nt][1] + rv.y, 0.f);
      const float h2v = fmaxf(acc[nt][2] + rv.z, 0.f);
      const float h3v = fmaxf(acc[nt][3] + rv.w, 0.f);
      p0 += h0v * wa.x + h1v * wa.z + h2v * wb.x + h3v * wb.z;
      p1 += h0v * wa.y + h1v * wa.w + h2v * wb.y + h3v * wb.w;
    }
    p0 += __shfl_xor(p0, 16); p1 += __shfl_xor(p1, 16);     // reduce over ag
    p0 += __shfl_xor(p0, 32); p1 += __shfl_xor(p1, 32);
    if (ag == 0 && row < nrows) {     // unique writer: tiles disjoint per wave
      po[row][0] = p0;
      po[row][1] = p1;
    }
  }

  __syncthreads();   // all po stores visible

  // fused cumsum + writeout: one thread per batch item
  if (tid < nb) {
    const int gb = lists[lbase + tid];
    const float bb0 = b2[e * OUT_DIM + 0];
    const float bb1 = b2[e * OUT_DIM + 1];
    float v[NWP * OUT_DIM];
    float s0 = 0.f, s1 = 0.f;
    #pragma unroll
    for (int n = 0; n < NWP; ++n) {
      s0 += po[tid * NWP + n][0] + bb0;
      s1 += po[tid * NWP + n][1] + bb1;
      v[n * 2 + 0] = s0;
      v[n * 2 + 1] = s1;
    }
    float4* op = (float4*)(out + (size_t)gb * NWP * OUT_DIM);
    #pragma unroll
    for (int q = 0; q < 5; ++q)
      op[q] = make_float4(v[q * 4], v[q * 4 + 1], v[q * 4 + 2], v[q * 4 + 3]);
  }
}

extern "C" void kernel_launch(void* const* d_in, const int* in_sizes, int n_in,
                              void* d_out, int out_size, void* d_ws, size_t ws_size,
                              hipStream_t stream) {
  const float* x          = (const float*)d_in[0];
  const int*   meas       = (const int*)d_in[1];
  const float* rank_embed = (const float*)d_in[2];
  const float* W1         = (const float*)d_in[3];
  const float* b1         = (const float*)d_in[4];
  const float* W2         = (const float*)d_in[5];
  const float* b2         = (const float*)d_in[6];
  float* out = (float*)d_out;

  int* qmeta = (int*)d_ws;                                       // counts[6]
  int* lists = (int*)((char*)d_ws + 8192);                       // 768 KB
  short* W1T = (short*)((char*)d_ws + (800 << 10));              // 192 KB bf16
  float* rw  = (float*)((char*)d_ws + (1000 << 10));             // 15.4 KB f32

  hipMemsetAsync(d_ws, 0, 256, stream);   // zero counts
  aux_k<<<50, 1024, 0, stream>>>(meas, W1, rank_embed, b1, qmeta, lists, W1T, rw);
  moe_gemm_k<<<MAXQ, 256, 0, stream>>>(x, W1T, rw, W2, b2, qmeta, lists, out);
}